// Round 6
// baseline (151.212 us; speedup 1.0000x reference)
//
#include <hip/hip_runtime.h>
#include <stdint.h>

#define B 1024
#define F 256
#define D 64

typedef __attribute__((ext_vector_type(8))) _Float16 half8;
typedef __attribute__((ext_vector_type(4))) float f32x4;

// ---------------------------------------------------------------------------
// Workspace layout:
//   trans : 2*F*D f32
//   qkv   : 3*F*D f32
//   gS    : B*F   f32     (s0*s2 row scale, per batch)
//   At    : [F/32][F][32] f16    (gate*cross, K-tiled)      = 128 KB
//   q2K   : [F/32][64][32] f16   (qkv2^T, K-tiled, d-PERMUTED: physical slot
//                                 p=(d&3)*16+(d>>2) so fragment nt at lane l16
//                                 holds logical col l16*4+nt -> float4 stores)
//   s1S   : B*F   f16     (s1 column scale, per batch)
// All GEMM operands f16 (not bf16): 10-bit mantissa (more accurate than bf16),
// range fine (|At|<~60, |s1*q2|<~300), and the s1*q2 scale becomes native
// v_pk_mul_f16 (half8*half8) -> no unpack/mul/repack VALU chain.
// ---------------------------------------------------------------------------

// Kernel A: trans/qkv = indicator @ W
__global__ void precompute_trans(const float* __restrict__ indicator,
                                 const float* __restrict__ W_qk,
                                 const float* __restrict__ W_qkv,
                                 float* __restrict__ trans,
                                 float* __restrict__ qkv) {
    int idx = blockIdx.x * blockDim.x + threadIdx.x;   // 0 .. 5*F*D
    int n   = idx / (F * D);
    int rem = idx - n * (F * D);
    int f   = rem / D;
    int e   = rem - f * D;
    const float* W = (n < 2) ? (W_qk + n * D * D) : (W_qkv + (n - 2) * D * D);
    const float* ind = indicator + f * D;
    float acc = 0.f;
#pragma unroll 8
    for (int d = 0; d < D; ++d) acc += ind[d] * W[d * D + e];
    if (n < 2) trans[n * F * D + f * D + e] = acc;
    else       qkv[(n - 2) * F * D + f * D + e] = acc;
}

// Merged kernel (512 threads):
//   blocks [0, B/2)          -> compute_s for 2 batches each (4-lane reduce)
//   blocks [B/2, B/2 + F/2)  -> compute_Mt, 2 columns per block
__global__ __launch_bounds__(512) void s_and_Mt(const float* __restrict__ feature,
                                                const float* __restrict__ trans,
                                                const float* __restrict__ qkv,
                                                float* __restrict__ gS,
                                                _Float16* __restrict__ s1S,
                                                _Float16* __restrict__ At,
                                                _Float16* __restrict__ q2K) {
    int blk = blockIdx.x;
    int tid = threadIdx.x;
    if (blk < B / 2) {
        // ---- compute_s: s[n,b,f] = feature[b,f,:].qkv[n,f,:] ----
        // 4 lanes per f-row (each lane owns 4 float4), 128 rows in flight.
        int b0 = blk * 2;
        int rg = tid >> 2;          // f-row group, 0..127
        int l  = tid & 3;           // lane-in-row
#pragma unroll
        for (int p = 0; p < 2; ++p) {
            int f = p * 128 + rg;
            const float4* fp0 = (const float4*)(feature + ((size_t)(b0 * F + f)) * D);
            const float4* fp1 = (const float4*)(feature + ((size_t)((b0 + 1) * F + f)) * D);
            const float4* qp0 = (const float4*)(qkv + f * D);
            const float4* qp1 = (const float4*)(qkv + F * D + f * D);
            const float4* qp2 = (const float4*)(qkv + 2 * F * D + f * D);
            float a00 = 0.f, a01 = 0.f, a02 = 0.f, a10 = 0.f, a11 = 0.f, a12 = 0.f;
#pragma unroll
            for (int t = 0; t < 4; ++t) {
                int k = l + 4 * t;   // adjacent lanes -> adjacent float4 (coalesced)
                float4 fv0 = fp0[k], fv1 = fp1[k];
                float4 q0 = qp0[k], q1 = qp1[k], q2 = qp2[k];
                a00 += fv0.x * q0.x + fv0.y * q0.y + fv0.z * q0.z + fv0.w * q0.w;
                a01 += fv0.x * q1.x + fv0.y * q1.y + fv0.z * q1.z + fv0.w * q1.w;
                a02 += fv0.x * q2.x + fv0.y * q2.y + fv0.z * q2.z + fv0.w * q2.w;
                a10 += fv1.x * q0.x + fv1.y * q0.y + fv1.z * q0.z + fv1.w * q0.w;
                a11 += fv1.x * q1.x + fv1.y * q1.y + fv1.z * q1.z + fv1.w * q1.w;
                a12 += fv1.x * q2.x + fv1.y * q2.y + fv1.z * q2.z + fv1.w * q2.w;
            }
#pragma unroll
            for (int m = 1; m < 4; m <<= 1) {
                a00 += __shfl_xor(a00, m, 64);
                a01 += __shfl_xor(a01, m, 64);
                a02 += __shfl_xor(a02, m, 64);
                a10 += __shfl_xor(a10, m, 64);
                a11 += __shfl_xor(a11, m, 64);
                a12 += __shfl_xor(a12, m, 64);
            }
            if (l == 0) {
                gS[b0 * F + f]        = a00 * a02;
                gS[(b0 + 1) * F + f]  = a10 * a12;
                s1S[b0 * F + f]       = (_Float16)a01;
                s1S[(b0 + 1) * F + f] = (_Float16)a11;
            }
        }
    } else {
        // ---- compute_Mt: At[(j>>5)][i][j&31] = gate(i,j) ? qkv1[i].qkv0[j] : 0
        //      q2K[(i>>5)][p(j)][i&31] = qkv2[i][j], p(j)=(j&3)*16+(j>>2) ----
        int j = (blk - B / 2) * 2 + (tid >> 8);   // 2 columns per block
        int i = tid & 255;
        const float4* t0 = (const float4*)(trans + i * D);
        const float4* t1 = (const float4*)(trans + F * D + j * D);
        const float4* q1 = (const float4*)(qkv + F * D + i * D);
        const float4* q0 = (const float4*)(qkv + j * D);
        float d0 = 0.f, d1 = 0.f;
#pragma unroll
        for (int k = 0; k < D / 4; ++k) {
            float4 a = t0[k], b = t1[k], c = q1[k], e = q0[k];
            d0 += a.x * b.x + a.y * b.y + a.z * b.z + a.w * b.w;
            d1 += c.x * e.x + c.y * e.y + c.z * e.z + c.w * e.w;
        }
        float v = (d0 > 0.f) ? d1 : 0.f;
        At[((j >> 5) * F + i) * 32 + (j & 31)] = (_Float16)v;
        if (j < D) {
            int p = (j & 3) * 16 + (j >> 2);   // d-permutation for float4 stores
            q2K[((i >> 5) * D + p) * 32 + (i & 31)] = (_Float16)qkv[2 * F * D + i * D + j];
        }
    }
}

// Kernel G: out[b,i,d] = gS[b,i] * sum_j At[i,j] * s1[b,j] * q2[j,d]
// Block = (batch-group of 8, i-tile of 64 rows); 512 threads / 8 waves.
// Wave w handles batch bg*8+w over the shared i-tile.
// At i-slice (32 KB) + q2K (32 KB) staged ONCE into LDS.
// B-fragment = q2 half8 * s1 half8 -> 4x v_pk_mul_f16, no repack chain.
__global__ __launch_bounds__(512, 4) void gemm_out(const _Float16* __restrict__ At,
                                                   const _Float16* __restrict__ q2K,
                                                   const float* __restrict__ gS,
                                                   const _Float16* __restrict__ s1S,
                                                   float* __restrict__ out) {
    int it  = blockIdx.x & 3;        // i-tile: rows [it*64, it*64+64)
    int bg  = blockIdx.x >> 2;       // batch-group of 8
    int tid = threadIdx.x;

    __shared__ __align__(16) _Float16 AtL[8 * 64 * 32];   // 32 KB: [jt][row 0..63][32]
    __shared__ __align__(16) _Float16 q2L[8 * 64 * 32];   // 32 KB: [jt][slot 0..63][32]

    // ---- stage At i-slice + q2K into LDS (coalesced float4 copies) ----
    {
        const float4* Ag = (const float4*)At;
        const float4* Qg = (const float4*)q2K;
        float4* Al = (float4*)AtL;
        float4* Ql = (float4*)q2L;
#pragma unroll
        for (int v = tid; v < 2048; v += 512) {
            int jt = v >> 8, k = v & 255;                 // 256 float4 per jt-chunk
            Al[v] = Ag[jt * 1024 + it * 256 + k];         // global chunk stride = 1024 f4
        }
#pragma unroll
        for (int v = tid; v < 2048; v += 512) Ql[v] = Qg[v];
    }
    __syncthreads();

    int w    = tid >> 6;        // wave -> batch
    int lane = tid & 63;
    int l16  = lane & 15;
    int lq   = lane >> 4;
    int kq   = lq * 8;
    int b    = bg * 8 + w;

    const _Float16* s1b = s1S + b * F;

    f32x4 acc[4][4];
#pragma unroll
    for (int mt = 0; mt < 4; ++mt)
#pragma unroll
        for (int nt = 0; nt < 4; ++nt) acc[mt][nt] = (f32x4){0.f, 0.f, 0.f, 0.f};

    for (int jt = 0; jt < F / 32; ++jt) {
        // s1 fragment (8 f16 along k) — direct pk-mul operand, no conversion
        half8 sv = *(const half8*)(s1b + jt * 32 + kq);

        // B fragments: q2 slot nt*16+l16 (logical d=l16*4+nt) * s1 — packed f16 mul
        half8 bfr[4];
#pragma unroll
        for (int nt = 0; nt < 4; ++nt) {
            int d = nt * 16 + l16;
            half8 qv = *(const half8*)(q2L + (jt * 64 + d) * 32 + kq);
            bfr[nt] = qv * sv;   // 4x v_pk_mul_f16
        }
        // A fragments from LDS + MFMA over the 64-row i-tile
#pragma unroll
        for (int mt = 0; mt < 4; ++mt) {
            half8 af = *(const half8*)(AtL + (jt * 64 + mt * 16 + l16) * 32 + kq);
#pragma unroll
            for (int nt = 0; nt < 4; ++nt)
                acc[mt][nt] = __builtin_amdgcn_mfma_f32_16x16x32_f16(
                    af, bfr[nt], acc[mt][nt], 0, 0, 0);
        }
    }

    // ---- epilogue: gS row scale + float4 stores (cols l16*4 .. l16*4+3) ----
    const float4* g4 = (const float4*)(gS + b * F + it * 64);
#pragma unroll
    for (int mt = 0; mt < 4; ++mt) {
        float4 gg = g4[mt * 4 + lq];   // rows it*64 + mt*16 + lq*4 .. +3
        float* obase = out + ((size_t)(b * F + it * 64 + mt * 16 + lq * 4)) * D + l16 * 4;
        float4 v0 = {gg.x * acc[mt][0][0], gg.x * acc[mt][1][0],
                     gg.x * acc[mt][2][0], gg.x * acc[mt][3][0]};
        float4 v1 = {gg.y * acc[mt][0][1], gg.y * acc[mt][1][1],
                     gg.y * acc[mt][2][1], gg.y * acc[mt][3][1]};
        float4 v2 = {gg.z * acc[mt][0][2], gg.z * acc[mt][1][2],
                     gg.z * acc[mt][2][2], gg.z * acc[mt][3][2]};
        float4 v3 = {gg.w * acc[mt][0][3], gg.w * acc[mt][1][3],
                     gg.w * acc[mt][2][3], gg.w * acc[mt][3][3]};
        *(float4*)(obase + 0 * D) = v0;
        *(float4*)(obase + 1 * D) = v1;
        *(float4*)(obase + 2 * D) = v2;
        *(float4*)(obase + 3 * D) = v3;
    }
}

extern "C" void kernel_launch(void* const* d_in, const int* in_sizes, int n_in,
                              void* d_out, int out_size, void* d_ws, size_t ws_size,
                              hipStream_t stream) {
    const float* feature   = (const float*)d_in[0];
    const float* indicator = (const float*)d_in[1];
    const float* W_qk      = (const float*)d_in[2];
    const float* W_qkv     = (const float*)d_in[3];
    float* out = (float*)d_out;

    float* ws    = (float*)d_ws;
    float* trans = ws;                              // 2*F*D f32
    float* qkv   = trans + 2 * F * D;               // 3*F*D f32
    float* gS    = qkv + 3 * F * D;                 // B*F f32
    _Float16* At  = (_Float16*)(gS + B * F);        // F*F f16 (K-tiled)
    _Float16* q2K = At + F * F;                     // (F/32)*64*32 f16 (K-tiled, permuted)
    _Float16* s1S = q2K + (F / 32) * D * 32;        // B*F f16

    hipLaunchKernelGGL(precompute_trans, dim3((5 * F * D) / 256), dim3(256), 0,
                       stream, indicator, W_qk, W_qkv, trans, qkv);
    hipLaunchKernelGGL(s_and_Mt, dim3(B / 2 + F / 2), dim3(512), 0, stream,
                       feature, trans, qkv, gS, s1S, At, q2K);
    hipLaunchKernelGGL(gemm_out, dim3((B / 8) * 4), dim3(512), 0, stream,
                       At, q2K, gS, s1S, out);
}